// Round 2
// baseline (17309.511 us; speedup 1.0000x reference)
//
#include <hip/hip_runtime.h>
#include <hip/hip_bf16.h>
#include <math.h>

// Problem dims
#define B_  128
#define T_  512
#define I_  256
#define H_  512
#define O_  256
#define NP  2048            // 4*H (gate-interleaved n' = h*4+g)
#define BT  65536           // B*T
#define HB  65536           // H*B
#define NBLK 256            // persistent scan grid size (== #CUs)

// ---------------------------------------------------------------------------
// Prep: build transposed/gathered weight layouts + fused bias vectors.
//  Wt  [K=512][NP]   : Wt[k][h*4+g]   = Wh_g[h][k]      (recurrent, transposed+interleaved)
//  Wg  [NP][I]       : Wg[h*4+g][i]   = Wx_g[h][i]      (x-weights, gathered rows for GEMM A)
//  WgT [I][NP]       : WgT[i][h*4+g]  = Wx_g[h][i]      (for fallback in-step x projection)
//  WphT[H][O]        : WphT[h][o]     = Wph[o][h]
//  xb  [NP]          : Wx_b_g[h] + b_g[h]
//  hb  [NP]          : Wh_b_g[h]
//  pb  [O]           : Wph_b[o] + bp[o]
// ---------------------------------------------------------------------------
struct PrepArgs {
    const float* Whw[4];
    const float* Wxw[4];
    const float* Wxb[4];
    const float* Whb[4];
    const float* bg[4];
    const float* Wph_w;
    const float* Wph_b;
    const float* bp;
    float* Wt; float* Wg; float* WgT; float* WphT;
    float* xb; float* hb; float* pb;
};

#define PREP_TOTAL (1048576 + 524288 + 524288 + 131072 + 2048 + 2048 + 256)

__global__ __launch_bounds__(256) void k_prep(PrepArgs a) {
    int idx = blockIdx.x * 256 + threadIdx.x;
    if (idx >= PREP_TOTAL) return;
    int q = idx;
    if (q < 1048576) {                       // Wt [512][2048]
        int k = q >> 11, n = q & 2047;
        int g = n & 3, h = n >> 2;
        a.Wt[q] = a.Whw[g][h * H_ + k];
        return;
    }
    q -= 1048576;
    if (q < 524288) {                        // Wg [2048][256]
        int n = q >> 8, i = q & 255;
        int g = n & 3, h = n >> 2;
        a.Wg[q] = a.Wxw[g][h * I_ + i];
        return;
    }
    q -= 524288;
    if (q < 524288) {                        // WgT [256][2048]
        int i = q >> 11, n = q & 2047;
        int g = n & 3, h = n >> 2;
        a.WgT[q] = a.Wxw[g][h * I_ + i];
        return;
    }
    q -= 524288;
    if (q < 131072) {                        // WphT [512][256]
        int h = q >> 8, o = q & 255;
        a.WphT[q] = a.Wph_w[o * H_ + h];
        return;
    }
    q -= 131072;
    if (q < 2048) {                          // xb
        int g = q & 3, h = q >> 2;
        a.xb[q] = a.Wxb[g][h] + a.bg[g][h];
        return;
    }
    q -= 2048;
    if (q < 2048) {                          // hb
        int g = q & 3, h = q >> 2;
        a.hb[q] = a.Whb[g][h];
        return;
    }
    q -= 2048;
    a.pb[q] = a.Wph_b[q] + a.bp[q];          // pb
}

// ---------------------------------------------------------------------------
// Transpose x: xT2[i][t*128+b] = x[b][t][i]
// ---------------------------------------------------------------------------
__global__ __launch_bounds__(256) void k_transpose(const float* __restrict__ x,
                                                   float* __restrict__ xT2) {
    __shared__ float lds[32][33];
    int tid = threadIdx.x;
    int tx = tid & 31, ty = tid >> 5;       // 32 x 8
    int j0 = blockIdx.x * 32;               // j = t*128 + b
    int i0 = blockIdx.y * 32;
    int t  = j0 >> 7;
    int b0 = j0 & 127;
#pragma unroll
    for (int rr = 0; rr < 4; ++rr) {
        int jj = ty + rr * 8;
        lds[jj][tx] = x[((size_t)(b0 + jj) * T_ + t) * I_ + i0 + tx];
    }
    __syncthreads();
#pragma unroll
    for (int rr = 0; rr < 4; ++rr) {
        int ii = ty + rr * 8;
        xT2[(size_t)(i0 + ii) * BT + j0 + tx] = lds[tx][ii];
    }
}

// ---------------------------------------------------------------------------
// Big input-projection GEMM: xp[m][j] = sum_i Wg[m][i]*xT2[i][j] + xb[m]
// ---------------------------------------------------------------------------
__global__ __launch_bounds__(256, 1) void k_xgemm(const float* __restrict__ A,
                                                  const float* __restrict__ Bm,
                                                  const float* __restrict__ bias,
                                                  float* __restrict__ C) {
    __shared__ float As[16][128];
    __shared__ float Bs[16][128];
    int tid = threadIdx.x;
    int tx = tid & 15, ty = tid >> 4;
    int m0 = blockIdx.y * 128, j0 = blockIdx.x * 128;
    float acc[8][8];
#pragma unroll
    for (int i = 0; i < 8; ++i)
#pragma unroll
        for (int j = 0; j < 8; ++j) acc[i][j] = 0.f;

    for (int kt = 0; kt < I_; kt += 16) {
#pragma unroll
        for (int pp = 0; pp < 2; ++pp) {
            int p = tid + pp * 256;
            int row = p >> 2, kq = (p & 3) << 2;
            float4 av = *(const float4*)&A[(size_t)(m0 + row) * I_ + kt + kq];
            As[kq + 0][row] = av.x; As[kq + 1][row] = av.y;
            As[kq + 2][row] = av.z; As[kq + 3][row] = av.w;
        }
#pragma unroll
        for (int pp = 0; pp < 2; ++pp) {
            int p = tid + pp * 256;
            int krow = p >> 5, c4 = (p & 31) << 2;
            *(float4*)&Bs[krow][c4] =
                *(const float4*)&Bm[(size_t)(kt + krow) * BT + j0 + c4];
        }
        __syncthreads();
#pragma unroll
        for (int k = 0; k < 16; ++k) {
            float a[8], b[8];
            *(float4*)&a[0] = *(const float4*)&As[k][ty * 4];
            *(float4*)&a[4] = *(const float4*)&As[k][64 + ty * 4];
            *(float4*)&b[0] = *(const float4*)&Bs[k][tx * 4];
            *(float4*)&b[4] = *(const float4*)&Bs[k][64 + tx * 4];
#pragma unroll
            for (int i = 0; i < 8; ++i)
#pragma unroll
                for (int j = 0; j < 8; ++j) acc[i][j] += a[i] * b[j];
        }
        __syncthreads();
    }
#pragma unroll
    for (int i = 0; i < 8; ++i) {
        int mrow = (i < 4) ? (ty * 4 + i) : (64 + ty * 4 + (i - 4));
        int m = m0 + mrow;
        float bv = bias[m];
        float4 v0 = {acc[i][0] + bv, acc[i][1] + bv, acc[i][2] + bv, acc[i][3] + bv};
        float4 v1 = {acc[i][4] + bv, acc[i][5] + bv, acc[i][6] + bv, acc[i][7] + bv};
        *(float4*)&C[(size_t)m * BT + j0 + tx * 4] = v0;
        *(float4*)&C[(size_t)m * BT + j0 + 64 + tx * 4] = v1;
    }
}

// ---------------------------------------------------------------------------
// Persistent scan kernel: all 512 timesteps in ONE dispatch.
// Grid 256 blocks x 512 threads (8 waves). Block = (nt 0..127 -> 16 n' cols,
// bh 0..1 -> 64 batch). Weights staged in LDS once; c in registers; per-step
// device-scope grid barrier (bar[t] counts arrivals; release add / acquire
// fence for cross-XCD h visibility).
// ---------------------------------------------------------------------------
__device__ inline float sigm(float v) { return 1.f / (1.f + expf(-v)); }

template <bool USE_XP>
__global__ __launch_bounds__(512, 2) void k_scan(const float* __restrict__ Wt,   // [512][NP]
                                                 const float* __restrict__ WgT,  // [256][NP]
                                                 const float* __restrict__ xp,   // [NP][BT]
                                                 const float* __restrict__ xT2,  // [256][BT]
                                                 const float* __restrict__ xb,   // [NP]
                                                 const float* __restrict__ hb,   // [NP]
                                                 float* __restrict__ hist,       // [513][512][128]
                                                 int* __restrict__ bar) {        // [512]
    __shared__ float wlds[512][16];         // recurrent weights, this block's 16 cols
    __shared__ float wxlds[256][16];        // x-weights (fallback path only)
    __shared__ float red[8][16][64];        // cross-wave K reduction

    int tid = threadIdx.x;
    int wave = tid >> 6, lane = tid & 63;
    int nt = blockIdx.x >> 1, bh = blockIdx.x & 1;
    int n0 = nt * 16, b0 = bh * 64;

    // ---- one-time weight staging into LDS ----
    for (int p = tid; p < 2048; p += 512) {           // 512 k-rows x 4 float4
        int k = p >> 2, q = (p & 3) << 2;
        *(float4*)&wlds[k][q] = *(const float4*)&Wt[(size_t)k * NP + n0 + q];
    }
    if (!USE_XP) {
        for (int p = tid; p < 1024; p += 512) {
            int i = p >> 2, q = (p & 3) << 2;
            *(float4*)&wxlds[i][q] = *(const float4*)&WgT[(size_t)i * NP + n0 + q];
        }
    }

    // ---- epilogue-thread persistent state (tid < 256 owns one (h,b) cell) ----
    int h_i = tid >> 6, b_l = tid & 63;               // valid when tid<256
    float c_reg = 0.f;
    float hbv[4] = {0, 0, 0, 0}, xbv[4] = {0, 0, 0, 0};
    if (tid < 256) {
#pragma unroll
        for (int g = 0; g < 4; ++g) {
            hbv[g] = hb[n0 + h_i * 4 + g];
            if (!USE_XP) xbv[g] = xb[n0 + h_i * 4 + g];
        }
    }
    __syncthreads();

    int b = b0 + lane;
    int kc = wave * 64;                               // this wave's K chunk

    bool dead = false;
    for (int t = 0; t < T_; ++t) {
        // ---- partial dot products over this wave's 64 k ----
        const float* hp = hist + (size_t)t * HB + (size_t)kc * B_ + b;
        float acc[16];
#pragma unroll
        for (int j = 0; j < 16; ++j) acc[j] = 0.f;
        float hv[8];
#pragma unroll
        for (int u = 0; u < 8; ++u) hv[u] = hp[u * B_];
        for (int kb = 0; kb < 64; kb += 8) {
            float hn[8];
            if (kb + 8 < 64) {
                const float* hp2 = hp + (size_t)(kb + 8) * B_;
#pragma unroll
                for (int u = 0; u < 8; ++u) hn[u] = hp2[u * B_];
            }
#pragma unroll
            for (int u = 0; u < 8; ++u) {
                int k = kc + kb + u;
                float h0 = hv[u];
#pragma unroll
                for (int j4 = 0; j4 < 4; ++j4) {
                    float4 wv = *(const float4*)&wlds[k][j4 * 4];
                    acc[j4 * 4 + 0] += h0 * wv.x;
                    acc[j4 * 4 + 1] += h0 * wv.y;
                    acc[j4 * 4 + 2] += h0 * wv.z;
                    acc[j4 * 4 + 3] += h0 * wv.w;
                }
            }
#pragma unroll
            for (int u = 0; u < 8; ++u) hv[u] = hn[u];
        }
        if (!USE_XP) {                                // fold x-projection (I chunk 32/wave)
            int ic = wave * 32;
            const float* xpp = xT2 + (size_t)ic * BT + (size_t)t * B_ + b;
#pragma unroll 4
            for (int ii = 0; ii < 32; ++ii) {
                float xv = xpp[(size_t)ii * BT];
#pragma unroll
                for (int j4 = 0; j4 < 4; ++j4) {
                    float4 wv = *(const float4*)&wxlds[ic + ii][j4 * 4];
                    acc[j4 * 4 + 0] += xv * wv.x;
                    acc[j4 * 4 + 1] += xv * wv.y;
                    acc[j4 * 4 + 2] += xv * wv.z;
                    acc[j4 * 4 + 3] += xv * wv.w;
                }
            }
        }
#pragma unroll
        for (int j = 0; j < 16; ++j) red[wave][j][lane] = acc[j];
        __syncthreads();

        // ---- epilogue: gates + cell update + h write ----
        if (tid < 256) {
            float pre[4];
#pragma unroll
            for (int g = 0; g < 4; ++g) {
                int j = h_i * 4 + g;
                float s = red[0][j][b_l];
#pragma unroll
                for (int w = 1; w < 8; ++w) s += red[w][j][b_l];
                pre[g] = s + hbv[g];
            }
            if (USE_XP) {
#pragma unroll
                for (int g = 0; g < 4; ++g)
                    pre[g] += xp[(size_t)(n0 + h_i * 4 + g) * BT + (size_t)t * B_ + b0 + b_l];
            } else {
#pragma unroll
                for (int g = 0; g < 4; ++g) pre[g] += xbv[g];
            }
            float iv = sigm(pre[0]);
            float fv = sigm(pre[1]);
            float gv = tanhf(pre[2]);
            float ov = sigm(pre[3]);
            c_reg = gv * iv + c_reg * fv;
            hist[(size_t)(t + 1) * HB + (size_t)(nt * 4 + h_i) * B_ + b0 + b_l] =
                tanhf(c_reg) * ov;
        }
        __syncthreads();                              // h writes + red reads done

        // ---- device-scope grid barrier on bar[t] ----
        if (tid == 0) {
            __hip_atomic_fetch_add(&bar[t], 1, __ATOMIC_RELEASE,
                                   __HIP_MEMORY_SCOPE_AGENT);
            if (!dead) {
                int spins = 0;
                while (__hip_atomic_load(&bar[t], __ATOMIC_RELAXED,
                                         __HIP_MEMORY_SCOPE_AGENT) < NBLK) {
                    __builtin_amdgcn_s_sleep(2);
                    if (++spins > (1 << 20)) { dead = true; break; }
                }
            }
        }
        __syncthreads();
        __builtin_amdgcn_fence(__ATOMIC_ACQUIRE, "agent");  // inv L1/L2 -> fresh h
    }
}

// ---------------------------------------------------------------------------
// Output projection: pT[t][o][b] = sum_h hist[t+1][h][b]*WphT[h][o] + pb[o]
// ---------------------------------------------------------------------------
__global__ __launch_bounds__(256, 1) void k_outproj(const float* __restrict__ WphT,
                                                    const float* __restrict__ pb,
                                                    const float* __restrict__ hist,
                                                    float* __restrict__ pT) {
    __shared__ float red[4][16][64];
    int tid = threadIdx.x;
    int wave = tid >> 6, lane = tid & 63;
    int t = blockIdx.y;
    int ot = blockIdx.x >> 1, bh = blockIdx.x & 1;
    int o0 = ot * 16, b0 = bh * 64;
    int b = b0 + lane;

    const float* hrow = hist + (size_t)(t + 1) * HB;
    float acc[16];
#pragma unroll
    for (int j = 0; j < 16; ++j) acc[j] = 0.f;

    int k0 = wave * 128;
    const float* hp = hrow + (size_t)k0 * B_ + b;
    const float* wp = WphT + (size_t)k0 * O_ + o0;
    float hv[8];
#pragma unroll
    for (int u = 0; u < 8; ++u) hv[u] = hp[u * B_];
    for (int kb = 0; kb < 128; kb += 8) {
        float hn[8];
        if (kb + 8 < 128) {
            const float* hp2 = hp + (size_t)(kb + 8) * B_;
#pragma unroll
            for (int u = 0; u < 8; ++u) hn[u] = hp2[u * B_];
        }
#pragma unroll
        for (int u = 0; u < 8; ++u) {
            const float* w = wp + (size_t)(kb + u) * O_;
            float h0 = hv[u];
#pragma unroll
            for (int j = 0; j < 4; ++j) {
                float4 wv = *(const float4*)(w + j * 4);
                acc[j * 4 + 0] += h0 * wv.x;
                acc[j * 4 + 1] += h0 * wv.y;
                acc[j * 4 + 2] += h0 * wv.z;
                acc[j * 4 + 3] += h0 * wv.w;
            }
        }
#pragma unroll
        for (int u = 0; u < 8; ++u) hv[u] = hn[u];
    }
#pragma unroll
    for (int j = 0; j < 16; ++j) red[wave][j][lane] = acc[j];
    __syncthreads();

    int b_l = tid & 63, oi = tid >> 6;
    int bb = b0 + b_l;
#pragma unroll
    for (int g = 0; g < 4; ++g) {
        int j = oi * 4 + g;
        int o = o0 + j;
        float v = red[0][j][b_l] + red[1][j][b_l] + red[2][j][b_l] + red[3][j][b_l] + pb[o];
        pT[(size_t)t * (O_ * B_) + (size_t)o * B_ + bb] = v;
    }
}

// ---------------------------------------------------------------------------
// Softmax over O + layout change to d_out[b][t][o].
// ---------------------------------------------------------------------------
__global__ __launch_bounds__(256, 1) void k_softmax(const float* __restrict__ pT,
                                                    float* __restrict__ out) {
    __shared__ float sm[32][257];
    __shared__ float rmax[32][8];
    __shared__ float rsum[32][8];
    int tid = threadIdx.x;
    int t = blockIdx.x >> 2, bq = blockIdx.x & 3;
    int b0 = bq * 32;
    const float* src = pT + (size_t)t * (O_ * B_);

#pragma unroll 4
    for (int it = 0; it < 32; ++it) {
        int idx = it * 256 + tid;
        int o = idx >> 5, b_l = idx & 31;
        sm[b_l][o] = src[(size_t)o * B_ + b0 + b_l];
    }
    __syncthreads();

    int b_l = tid >> 3, oc = tid & 7;
    float m = -3.4e38f;
#pragma unroll 4
    for (int oo = 0; oo < 32; ++oo) m = fmaxf(m, sm[b_l][oc * 32 + oo]);
    rmax[b_l][oc] = m;
    __syncthreads();
    float mm = rmax[b_l][0];
#pragma unroll
    for (int c = 1; c < 8; ++c) mm = fmaxf(mm, rmax[b_l][c]);

    float s = 0.f;
#pragma unroll 4
    for (int oo = 0; oo < 32; ++oo) s += expf(sm[b_l][oc * 32 + oo] - mm);
    rsum[b_l][oc] = s;
    __syncthreads();
    float st = 0.f;
#pragma unroll
    for (int c = 0; c < 8; ++c) st += rsum[b_l][c];
    float inv = 1.f / st;

    int bb = b0 + b_l;
    float* dst = out + ((size_t)bb * T_ + t) * O_ + oc * 32;
#pragma unroll 4
    for (int oo = 0; oo < 32; ++oo)
        dst[oo] = expf(sm[b_l][oc * 32 + oo] - mm) * inv;
}

// ---------------------------------------------------------------------------
extern "C" void kernel_launch(void* const* d_in, const int* in_sizes, int n_in,
                              void* d_out, int out_size, void* d_ws, size_t ws_size,
                              hipStream_t stream) {
    const float* x = (const float*)d_in[0];

    float* ws = (float*)d_ws;
    size_t off = 0;
    auto alloc = [&](size_t n) { float* p = ws + off; off += n; return p; };

    float* hist = alloc((size_t)513 * HB);      // h history (slot 0 = h_{-1} = 0)
    float* Wt   = alloc((size_t)512 * NP);
    float* Wg   = alloc((size_t)NP * I_);
    float* WgT  = alloc((size_t)I_ * NP);
    float* WphT = alloc((size_t)H_ * O_);
    float* xb   = alloc(NP);
    float* hb   = alloc(NP);
    float* pb   = alloc(O_);
    int*   bar  = (int*)alloc(512);             // grid-barrier counters
    float* xT2  = alloc((size_t)I_ * BT);       // reused as pT after the scan
    size_t baseBytes = off * sizeof(float);
    size_t xpBytes   = (size_t)NP * BT * sizeof(float);

    bool useXp = (ws_size >= baseBytes + xpBytes);
    float* xp = ws + off;                       // only valid if useXp
    float* pT = xT2;

    if (ws_size < baseBytes) return;            // cannot run — fail cleanly

    hipMemsetAsync(hist, 0, HB * sizeof(float), stream);   // h_{-1} = 0
    hipMemsetAsync(bar, 0, 512 * sizeof(int), stream);     // barrier counters

    PrepArgs pa;
    for (int g = 0; g < 4; ++g) {
        pa.Wxw[g] = (const float*)d_in[1 + 5 * g];
        pa.Wxb[g] = (const float*)d_in[2 + 5 * g];
        pa.Whw[g] = (const float*)d_in[3 + 5 * g];
        pa.Whb[g] = (const float*)d_in[4 + 5 * g];
        pa.bg[g]  = (const float*)d_in[5 + 5 * g];
    }
    pa.Wph_w = (const float*)d_in[21];
    pa.Wph_b = (const float*)d_in[22];
    pa.bp    = (const float*)d_in[23];
    pa.Wt = Wt; pa.Wg = Wg; pa.WgT = WgT; pa.WphT = WphT;
    pa.xb = xb; pa.hb = hb; pa.pb = pb;

    k_prep<<<(PREP_TOTAL + 255) / 256, 256, 0, stream>>>(pa);
    k_transpose<<<dim3(BT / 32, I_ / 32), 256, 0, stream>>>(x, xT2);

    if (useXp) {
        k_xgemm<<<dim3(BT / 128, NP / 128), 256, 0, stream>>>(Wg, xT2, xb, xp);
        k_scan<true><<<NBLK, 512, 0, stream>>>(Wt, WgT, xp, xT2, xb, hb, hist, bar);
    } else {
        k_scan<false><<<NBLK, 512, 0, stream>>>(Wt, WgT, xp, xT2, xb, hb, hist, bar);
    }

    k_outproj<<<dim3(32, T_), 256, 0, stream>>>(WphT, pb, hist, pT);
    k_softmax<<<T_ * 4, 256, 0, stream>>>(pT, (float*)d_out);
}